// Round 1
// baseline (162.979 us; speedup 1.0000x reference)
//
#include <hip/hip_runtime.h>
#include <hip/hip_bf16.h>
#include <stdint.h>

// Problem constants (from reference)
#define B_   32
#define C_   3
#define H_   384
#define W_   384
#define N_   576
#define ED   768            // embed dim (output features)
#define KF   768            // in features = 3*16*16
#define M_   (B_ * N_)      // 18432 patch rows

typedef __attribute__((ext_vector_type(8))) short   short8;
typedef __attribute__((ext_vector_type(8))) unsigned short ushort8;
typedef __attribute__((ext_vector_type(4))) float   f32x4;

// fp32 -> bf16 with round-to-nearest-even
__device__ __forceinline__ unsigned short f2bf(float f) {
    union { float f; unsigned int u; } v; v.f = f;
    unsigned int u = v.u;
    return (unsigned short)((u + 0x7FFFu + ((u >> 16) & 1u)) >> 16);
}

// ---------------------------------------------------------------------------
// Kernel 1: gather patches -> bf16 A matrix [M_][KF], row-major.
// f = c*256 + ph*16 + pw  (reference transpose (0,1,4,2,3) ordering).
// Each thread handles 8 contiguous k (half a pw-row): 32B contiguous x read,
// one 16B bf16 write. 96 threads per patch.
// ---------------------------------------------------------------------------
__global__ __launch_bounds__(256) void gather_patches(
    const float* __restrict__ x, const int* __restrict__ h_idx,
    const int* __restrict__ w_idx, unsigned short* __restrict__ Aws) {
    int gid = blockIdx.x * 256 + threadIdx.x;          // M_*96 total threads
    int m   = gid / 96;
    int kb  = gid - m * 96;
    int k0  = kb * 8;
    int b   = m / N_;
    int c   = k0 >> 8;            // k0 / 256
    int rem = k0 & 255;
    int ph  = rem >> 4;
    int pw  = rem & 15;           // 0 or 8
    int h = h_idx[m] + ph;
    int w = w_idx[m] + pw;
    const float* src = x + (((b * C_ + c) * H_ + h) * (long)W_ + w);
    ushort8 o;
#pragma unroll
    for (int i = 0; i < 8; ++i) o[i] = f2bf(src[i]);
    *(ushort8*)(Aws + (size_t)m * KF + k0) = o;
}

// ---------------------------------------------------------------------------
// Kernel 2: proj_w fp32 -> bf16 [ED][KF] row-major (B^T layout, K contiguous)
// ---------------------------------------------------------------------------
__global__ __launch_bounds__(256) void conv_w(
    const float* __restrict__ w, unsigned short* __restrict__ Wb) {
    int gid = blockIdx.x * 256 + threadIdx.x;          // ED*KF/8 threads
    const float4* s = (const float4*)w + (size_t)gid * 2;
    float4 a = s[0], bq = s[1];
    ushort8 o;
    o[0] = f2bf(a.x);  o[1] = f2bf(a.y);  o[2] = f2bf(a.z);  o[3] = f2bf(a.w);
    o[4] = f2bf(bq.x); o[5] = f2bf(bq.y); o[6] = f2bf(bq.z); o[7] = f2bf(bq.w);
    *(ushort8*)(Wb + (size_t)gid * 8) = o;
}

// ---------------------------------------------------------------------------
// Kernel 3: bf16 GEMM, m97 structure: out[m][e] = sum_k A[m][k]*W[e][k] + b[e]
// 128x128 tile, BK=32, 4 waves in 2x2, each wave a 64x64 sub-tile (4x4 frags
// of 16x16), mfma_f32_16x16x32_bf16, global_load_lds width=16 staging.
// ---------------------------------------------------------------------------
#define GLD16(g, l)                                                        \
    __builtin_amdgcn_global_load_lds(                                      \
        (const __attribute__((address_space(1))) unsigned int*)(g),        \
        (__attribute__((address_space(3))) unsigned int*)(l), 16, 0, 0)

__global__ __launch_bounds__(256) void gemm_bt(
    const unsigned short* __restrict__ A, const unsigned short* __restrict__ Wb,
    const float* __restrict__ bias, float* __restrict__ out) {
    __shared__ unsigned short sA[128 * 32];   // 8 KiB
    __shared__ unsigned short sB[128 * 32];   // 8 KiB

    const int t    = threadIdx.x;
    const int m0   = blockIdx.y * 128;
    const int e0   = blockIdx.x * 128;
    const int lane = t & 63;
    const int wid  = t >> 6;
    const int wr   = wid >> 1;       // wave row (0..1)
    const int wc   = wid & 1;        // wave col (0..1)
    const int r16  = lane & 15;
    const int kh   = lane >> 4;      // 0..3, k-offset = kh*8

    f32x4 acc[4][4];
#pragma unroll
    for (int i = 0; i < 4; ++i)
#pragma unroll
        for (int j = 0; j < 4; ++j) acc[i][j] = (f32x4)0.0f;

    for (int kt = 0; kt < KF / 32; ++kt) {
        const int k0 = kt * 32;
        // Stage A-tile and B-tile (8 KiB each) with 16B global_load_lds.
        // Linear byte offset o: row = o/64 (64B per 32-bf16 row), LDS dest is
        // wave-uniform base + lane*16 (rnd*4096 + w*1024 + lane*16). [m97]
#pragma unroll
        for (int rnd = 0; rnd < 2; ++rnd) {
            const int o    = rnd * 4096 + t * 16;   // bytes
            const int row  = o >> 6;
            const int cole = (o & 63) >> 1;         // element col within 32
            GLD16(A  + (size_t)(m0 + row) * KF + k0 + cole, (char*)sA + o);
            GLD16(Wb + (size_t)(e0 + row) * KF + k0 + cole, (char*)sB + o);
        }
        __syncthreads();   // compiler emits vmcnt(0) drain before barrier

        short8 af[4], bf[4];
#pragma unroll
        for (int mi = 0; mi < 4; ++mi)
            af[mi] = *(const short8*)&sA[(wr * 64 + mi * 16 + r16) * 32 + kh * 8];
#pragma unroll
        for (int ni = 0; ni < 4; ++ni)
            bf[ni] = *(const short8*)&sB[(wc * 64 + ni * 16 + r16) * 32 + kh * 8];
#pragma unroll
        for (int mi = 0; mi < 4; ++mi)
#pragma unroll
            for (int ni = 0; ni < 4; ++ni)
                acc[mi][ni] = __builtin_amdgcn_mfma_f32_16x16x32_bf16(
                    af[mi], bf[ni], acc[mi][ni], 0, 0, 0);
        __syncthreads();   // before next stage overwrites LDS
    }

    // Epilogue: C/D layout col = lane&15, row = (lane>>4)*4 + j  [m89]
#pragma unroll
    for (int mi = 0; mi < 4; ++mi) {
#pragma unroll
        for (int ni = 0; ni < 4; ++ni) {
            const int ge = e0 + wc * 64 + ni * 16 + r16;
            const float bv = bias[ge];
#pragma unroll
            for (int j = 0; j < 4; ++j) {
                const int gm = m0 + wr * 64 + mi * 16 + kh * 4 + j;
                out[(size_t)gm * ED + ge] = acc[mi][ni][j] + bv;
            }
        }
    }
}

// ---------------------------------------------------------------------------
extern "C" void kernel_launch(void* const* d_in, const int* in_sizes, int n_in,
                              void* d_out, int out_size, void* d_ws, size_t ws_size,
                              hipStream_t stream) {
    const float* x      = (const float*)d_in[0];
    const int*   h_idx  = (const int*)  d_in[1];
    const int*   w_idx  = (const int*)  d_in[2];
    const float* proj_w = (const float*)d_in[3];
    const float* proj_b = (const float*)d_in[4];
    float*       out    = (float*)d_out;

    // Workspace layout: A bf16 [M_][KF] (28,311,552 B) then Wb bf16 [ED][KF]
    // (1,179,648 B) — needs ws_size >= ~29.5 MB.
    unsigned short* Aws = (unsigned short*)d_ws;
    unsigned short* Wws = Aws + (size_t)M_ * KF;

    gather_patches<<<M_ * 96 / 256, 256, 0, stream>>>(x, h_idx, w_idx, Aws);
    conv_w<<<(ED * KF / 8) / 256, 256, 0, stream>>>(proj_w, Wws);
    gemm_bt<<<dim3(ED / 128, M_ / 128), 256, 0, stream>>>(Aws, Wws, proj_b, out);
}

// Round 4
// 153.168 us; speedup vs baseline: 1.0641x; 1.0641x over previous
//
#include <hip/hip_runtime.h>
#include <hip/hip_bf16.h>
#include <stdint.h>

// Problem constants (from reference)
#define B_   32
#define C_   3
#define H_   384
#define W_   384
#define N_   576
#define ED   768            // embed dim (output features)
#define KF   768            // in features = 3*16*16
#define M_   (B_ * N_)      // 18432 patch rows

typedef __attribute__((ext_vector_type(8))) short   short8;
typedef __attribute__((ext_vector_type(8))) unsigned short ushort8;
typedef __attribute__((ext_vector_type(4))) float   f32x4;

// fp32 -> bf16 with round-to-nearest-even
__device__ __forceinline__ unsigned short f2bf(float f) {
    union { float f; unsigned int u; } v; v.f = f;
    unsigned int u = v.u;
    return (unsigned short)((u + 0x7FFFu + ((u >> 16) & 1u)) >> 16);
}

// ---------------------------------------------------------------------------
// Kernel 1: gather patches -> bf16 A matrix [M_][KF], row-major.
// f = c*256 + ph*16 + pw  (reference transpose (0,1,4,2,3) ordering).
// (unchanged from round 1 — isolating the GEMM change this round)
// ---------------------------------------------------------------------------
__global__ __launch_bounds__(256) void gather_patches(
    const float* __restrict__ x, const int* __restrict__ h_idx,
    const int* __restrict__ w_idx, unsigned short* __restrict__ Aws) {
    int gid = blockIdx.x * 256 + threadIdx.x;          // M_*96 total threads
    int m   = gid / 96;
    int kb  = gid - m * 96;
    int k0  = kb * 8;
    int b   = m / N_;
    int c   = k0 >> 8;            // k0 / 256
    int rem = k0 & 255;
    int ph  = rem >> 4;
    int pw  = rem & 15;           // 0 or 8
    int h = h_idx[m] + ph;
    int w = w_idx[m] + pw;
    const float* src = x + (((b * C_ + c) * H_ + h) * (long)W_ + w);
    ushort8 o;
#pragma unroll
    for (int i = 0; i < 8; ++i) o[i] = f2bf(src[i]);
    *(ushort8*)(Aws + (size_t)m * KF + k0) = o;
}

// ---------------------------------------------------------------------------
// Kernel 2: proj_w fp32 -> bf16 [ED][KF] row-major (B^T layout, K contiguous)
// ---------------------------------------------------------------------------
__global__ __launch_bounds__(256) void conv_w(
    const float* __restrict__ w, unsigned short* __restrict__ Wb) {
    int gid = blockIdx.x * 256 + threadIdx.x;          // ED*KF/8 threads
    const float4* s = (const float4*)w + (size_t)gid * 2;
    float4 a = s[0], bq = s[1];
    ushort8 o;
    o[0] = f2bf(a.x);  o[1] = f2bf(a.y);  o[2] = f2bf(a.z);  o[3] = f2bf(a.w);
    o[4] = f2bf(bq.x); o[5] = f2bf(bq.y); o[6] = f2bf(bq.z); o[7] = f2bf(bq.w);
    *(ushort8*)(Wb + (size_t)gid * 8) = o;
}

// ---------------------------------------------------------------------------
// Kernel 3: bf16 GEMM: out[m][e] = sum_k A[m][k]*W[e][k] + b[e]
// 128x128 tile, BK=64 (12 K-iters, halved barrier count vs BK=32).
// T2 XOR swizzle: LDS rows are 128B = 8 x 16B slots; global SOURCE slot is
// pre-permuted g = s ^ (row&7) (global_load_lds writes linearly — rule #21),
// and ds_read applies the same XOR. Any 8 consecutive lanes then read 8
// distinct slots -> conflict-free ds_read_b128.
// Bijective XCD swizzle (864 blocks % 8 == 0): each XCD owns 18 contiguous
// m-tiles x all 6 e-tiles -> A panel (~3.5MB) L2-resident per XCD.
// ---------------------------------------------------------------------------
#define GLD16(g, l)                                                        \
    __builtin_amdgcn_global_load_lds(                                      \
        (const __attribute__((address_space(1))) unsigned int*)(g),        \
        (__attribute__((address_space(3))) unsigned int*)(l), 16, 0, 0)

#define BK 64

__global__ __launch_bounds__(256) void gemm_bt(
    const unsigned short* __restrict__ A, const unsigned short* __restrict__ Wb,
    const float* __restrict__ bias, float* __restrict__ out) {
    __shared__ unsigned short sA[128 * BK];   // 16 KiB
    __shared__ unsigned short sB[128 * BK];   // 16 KiB

    const int t = threadIdx.x;

    // XCD-aware block swizzle: dispatch-linear id -> (e_tile, m_tile)
    const int lin = blockIdx.y * 6 + blockIdx.x;     // x-fastest dispatch order
    const int swz = (lin & 7) * 108 + (lin >> 3);    // 864/8 = 108, bijective
    const int m0  = (swz / 6) * 128;
    const int e0  = (swz % 6) * 128;

    const int lane = t & 63;
    const int wid  = t >> 6;
    const int wr   = wid >> 1;       // wave row (0..1)
    const int wc   = wid & 1;        // wave col (0..1)
    const int r16  = lane & 15;
    const int kh   = lane >> 4;      // 0..3

    f32x4 acc[4][4];
#pragma unroll
    for (int i = 0; i < 4; ++i)
#pragma unroll
        for (int j = 0; j < 4; ++j) acc[i][j] = (f32x4)0.0f;

    // Precompute staging addressing (constant across K-iters except k0):
    // round r: byte o = r*4096 + t*16; row = o>>7; slot s = (o>>4)&7;
    // source slot g = s ^ (row&7); source col = g*8.
    int st_row[4], st_gc[4];
#pragma unroll
    for (int r = 0; r < 4; ++r) {
        const int o   = r * 4096 + t * 16;
        const int row = o >> 7;
        const int s   = (o >> 4) & 7;
        st_row[r] = row;
        st_gc[r]  = (s ^ (row & 7)) * 8;
    }

    for (int kt = 0; kt < KF / BK; ++kt) {
        const int k0 = kt * BK;
#pragma unroll
        for (int r = 0; r < 4; ++r) {
            const int o = r * 4096 + t * 16;
            GLD16(A  + (size_t)(m0 + st_row[r]) * KF + k0 + st_gc[r], (char*)sA + o);
            GLD16(Wb + (size_t)(e0 + st_row[r]) * KF + k0 + st_gc[r], (char*)sB + o);
        }
        __syncthreads();

#pragma unroll
        for (int kk = 0; kk < 2; ++kk) {
            short8 af[4], bf[4];
#pragma unroll
            for (int mi = 0; mi < 4; ++mi) {
                const int ar = wr * 64 + mi * 16 + r16;
                const int sl = ((kk << 2) + kh) ^ (ar & 7);
                af[mi] = *(const short8*)&sA[ar * BK + sl * 8];
            }
#pragma unroll
            for (int ni = 0; ni < 4; ++ni) {
                const int br = wc * 64 + ni * 16 + r16;
                const int sl = ((kk << 2) + kh) ^ (br & 7);
                bf[ni] = *(const short8*)&sB[br * BK + sl * 8];
            }
#pragma unroll
            for (int mi = 0; mi < 4; ++mi)
#pragma unroll
                for (int ni = 0; ni < 4; ++ni)
                    acc[mi][ni] = __builtin_amdgcn_mfma_f32_16x16x32_bf16(
                        af[mi], bf[ni], acc[mi][ni], 0, 0, 0);
        }
        __syncthreads();
    }

    // Epilogue: C/D layout col = lane&15, row = (lane>>4)*4 + j  [m89]
#pragma unroll
    for (int mi = 0; mi < 4; ++mi) {
#pragma unroll
        for (int ni = 0; ni < 4; ++ni) {
            const int ge = e0 + wc * 64 + ni * 16 + r16;
            const float bv = bias[ge];
#pragma unroll
            for (int j = 0; j < 4; ++j) {
                const int gm = m0 + wr * 64 + mi * 16 + kh * 4 + j;
                out[(size_t)gm * ED + ge] = acc[mi][ni][j] + bv;
            }
        }
    }
}

// ---------------------------------------------------------------------------
extern "C" void kernel_launch(void* const* d_in, const int* in_sizes, int n_in,
                              void* d_out, int out_size, void* d_ws, size_t ws_size,
                              hipStream_t stream) {
    const float* x      = (const float*)d_in[0];
    const int*   h_idx  = (const int*)  d_in[1];
    const int*   w_idx  = (const int*)  d_in[2];
    const float* proj_w = (const float*)d_in[3];
    const float* proj_b = (const float*)d_in[4];
    float*       out    = (float*)d_out;

    // Workspace: A bf16 [M_][KF] (28.3 MB) then Wb bf16 [ED][KF] (1.2 MB).
    unsigned short* Aws = (unsigned short*)d_ws;
    unsigned short* Wws = Aws + (size_t)M_ * KF;

    gather_patches<<<M_ * 96 / 256, 256, 0, stream>>>(x, h_idx, w_idx, Aws);
    conv_w<<<(ED * KF / 8) / 256, 256, 0, stream>>>(proj_w, Wws);
    gemm_bt<<<dim3(ED / 128, M_ / 128), 256, 0, stream>>>(Aws, Wws, proj_b, out);
}